// Round 17
// baseline (178.558 us; speedup 1.0000x reference)
//
#include <hip/hip_runtime.h>

#define T_SEQ 2048
#define D_MODEL 1024
#define NH 16
#define HD 64
#define BH_TOT 32          // B*H
#define M_ROWS 4096        // B*T
#define NT 32              // number of 64-row q tiles
#define SCALE 0.125f
#define BHT (BH_TOT * T_SEQ)
#define LOG2E 1.44269504f
#define TAU 2.885f         // defer-max threshold in log2 units (= e^2 in p-space)

typedef _Float16 h8 __attribute__((ext_vector_type(8)));
typedef _Float16 h4 __attribute__((ext_vector_type(4)));
typedef float f32x4 __attribute__((ext_vector_type(4)));

__device__ __forceinline__ f32x4 mfma_h(h8 a, h8 b, f32x4 c) {
    return __builtin_amdgcn_mfma_f32_16x16x32_f16(a, b, c, 0, 0, 0);
}

// async global->LDS, 16B per lane; LDS dest is wave-uniform base + lane*16
__device__ __forceinline__ void gload16(const _Float16* g, _Float16* l) {
    __builtin_amdgcn_global_load_lds(
        (const __attribute__((address_space(1))) unsigned int*)g,
        (__attribute__((address_space(3))) unsigned int*)l, 16, 0, 0);
}

// ---------------- convert f32 -> f16 (flat) ----------------
__global__ void k_convert(const float* __restrict__ in, _Float16* __restrict__ out, int n) {
    int i = (blockIdx.x * blockDim.x + threadIdx.x) * 4;
    if (i < n) {
        float4 v = *(const float4*)(in + i);
        h4 o;
        o[0] = (_Float16)v.x; o[1] = (_Float16)v.y;
        o[2] = (_Float16)v.z; o[3] = (_Float16)v.w;
        *(h4*)(out + i) = o;
    }
}

// ---------------- transpose+convert: in [K][N] f32 -> out [N][K] f16 ----------------
__global__ void k_transpose(const float* __restrict__ in, _Float16* __restrict__ out, int K, int N) {
    __shared__ float tile[32][33];
    int nb = blockIdx.x * 32, kb = blockIdx.y * 32;
    int tx = threadIdx.x & 31, ty = threadIdx.x >> 5;   // 256 thr: ty 0..7
    #pragma unroll
    for (int i = 0; i < 32; i += 8)
        tile[ty + i][tx] = in[(size_t)(kb + ty + i) * N + (nb + tx)];
    __syncthreads();
    #pragma unroll
    for (int i = 0; i < 32; i += 8)
        out[(size_t)(nb + ty + i) * K + (kb + tx)] = (_Float16)tile[tx][ty + i];
}

// ---------------- GEMM: C = A[M,K] @ Bt[N,K]^T + bias ----------------
// BK=64, double-buffered LDS staged via global_load_lds(16B), inverse-swizzled
// global source; fragment ds_read applies same XOR. (Best-measured structure.)
// MODE 0 epilogue: q->Qh, k->Kh + KF(fragment-major ks0,1), v->Vh + VF(fragment-major), t->Th
// MODE 1: plain f32 output C[M,N] + bias
template<int MODE>
__launch_bounds__(256, 2)
__global__ void k_gemm(const _Float16* __restrict__ A, const _Float16* __restrict__ Bt,
                       int M, int N, int K, const float* __restrict__ bias,
                       _Float16* __restrict__ qo, _Float16* __restrict__ kho,
                       _Float16* __restrict__ kfo, _Float16* __restrict__ vo,
                       _Float16* __restrict__ vfo, _Float16* __restrict__ to,
                       float* __restrict__ cOut)
{
    __shared__ __align__(16) _Float16 lA[2][128 * 64];
    __shared__ __align__(16) _Float16 lB[2][128 * 64];
    const int tid = threadIdx.x;
    const int wid = tid >> 6, lane = tid & 63, lrow = lane & 15, lg = lane >> 4;
    const int wm = wid >> 1, wn = wid & 1;
    const int m0 = blockIdx.x * 128, n0 = blockIdx.y * 128;

    f32x4 acc[4][4];
    #pragma unroll
    for (int i = 0; i < 4; i++)
        #pragma unroll
        for (int j = 0; j < 4; j++) acc[i][j] = (f32x4){0.f, 0.f, 0.f, 0.f};

    const int rin = lane >> 3, gcol = lane & 7;
    const int scol = (gcol ^ rin) * 8;          // inverse-swizzled source column
    const _Float16* gA = A + (size_t)(m0 + 32 * wid + rin) * K + scol;
    const _Float16* gB = Bt + (size_t)(n0 + 32 * wid + rin) * K + scol;

    const int r7 = lrow & 7;
    const int nk = K >> 6;

    #pragma unroll
    for (int i = 0; i < 4; i++) {
        gload16(gA + (size_t)(8 * i) * K, &lA[0][32 * wid * 64 + 8 * i * 64]);
        gload16(gB + (size_t)(8 * i) * K, &lB[0][32 * wid * 64 + 8 * i * 64]);
    }
    __syncthreads();

    for (int kt = 0; kt < nk; ++kt) {
        const int cur = kt & 1;
        if (kt + 1 < nk) {
            const size_t ko = (size_t)(kt + 1) * 64;
            #pragma unroll
            for (int i = 0; i < 4; i++) {
                gload16(gA + (size_t)(8 * i) * K + ko, &lA[cur ^ 1][32 * wid * 64 + 8 * i * 64]);
                gload16(gB + (size_t)(8 * i) * K + ko, &lB[cur ^ 1][32 * wid * 64 + 8 * i * 64]);
            }
        }
        h8 af[4][2], bfr[4][2];
        #pragma unroll
        for (int mi = 0; mi < 4; mi++) {
            const int row = wm * 64 + mi * 16 + lrow;
            af[mi][0] = *(const h8*)&lA[cur][row * 64 + ((lg ^ r7) * 8)];
            af[mi][1] = *(const h8*)&lA[cur][row * 64 + (((4 + lg) ^ r7) * 8)];
        }
        #pragma unroll
        for (int ni = 0; ni < 4; ni++) {
            const int row = wn * 64 + ni * 16 + lrow;
            bfr[ni][0] = *(const h8*)&lB[cur][row * 64 + ((lg ^ r7) * 8)];
            bfr[ni][1] = *(const h8*)&lB[cur][row * 64 + (((4 + lg) ^ r7) * 8)];
        }
        #pragma unroll
        for (int mi = 0; mi < 4; mi++)
            #pragma unroll
            for (int ni = 0; ni < 4; ni++) {
                acc[mi][ni] = mfma_h(af[mi][0], bfr[ni][0], acc[mi][ni]);
                acc[mi][ni] = mfma_h(af[mi][1], bfr[ni][1], acc[mi][ni]);
            }
        __syncthreads();
    }

    if (MODE == 0) {
        const int ssel = n0 >> 10;
        #pragma unroll
        for (int mi = 0; mi < 4; mi++) {
            #pragma unroll
            for (int ni = 0; ni < 4; ni++) {
                const int nn = n0 + wn * 64 + ni * 16 + lrow;
                const float bv = bias[nn];
                const int h = (nn >> 6) & 15, hd = nn & 63;
                const int mmb = m0 + wm * 64 + mi * 16 + 4 * lg;
                const int b = mmb >> 11, t0 = mmb & (T_SEQ - 1);
                const int bh = b * NH + h;
                const size_t rowb = (size_t)bh * T_SEQ;
                h4 hv;
                #pragma unroll
                for (int r = 0; r < 4; r++) hv[r] = (_Float16)(acc[mi][ni][r] + bv);
                if (ssel == 0) {
                    #pragma unroll
                    for (int r = 0; r < 4; r++) qo[(rowb + t0 + r) * HD + hd] = hv[r];
                } else if (ssel == 1) {
                    const int ksK = hd >> 5, lgK = (hd & 31) >> 3, iK = hd & 7;
                    #pragma unroll
                    for (int r = 0; r < 4; r++) {
                        const int t = t0 + r;
                        kho[(rowb + t) * HD + hd] = hv[r];
                        const int j = t >> 6, ct = (t >> 4) & 3;
                        const int laneF = (t & 15) | (lgK << 4);
                        kfo[(((size_t)bh * 32 + j) * 16 + ct * 4 + ksK) * 512 + laneF * 8 + iK] = hv[r];
                    }
                } else if (ssel == 2) {
                    #pragma unroll
                    for (int r = 0; r < 4; r++) vo[(rowb + t0 + r) * HD + hd] = hv[r];
                    const int ctV = hd >> 4, lrV = hd & 15;
                    const int j = t0 >> 6, ksV = (t0 >> 5) & 1, lgV = (t0 >> 3) & 3, i0 = t0 & 7;
                    const int laneF = lrV | (lgV << 4);
                    *(h4*)&vfo[(((size_t)bh * 32 + j) * 8 + ctV * 2 + ksV) * 512 + laneF * 8 + i0] = hv;
                } else {
                    #pragma unroll
                    for (int r = 0; r < 4; r++) to[(rowb + t0 + r) * HD + hd] = hv[r];
                }
            }
        }
    } else {
        #pragma unroll
        for (int mi = 0; mi < 4; mi++) {
            #pragma unroll
            for (int ni = 0; ni < 4; ni++) {
                const int nn = n0 + wn * 64 + ni * 16 + lrow;
                const float bv = bias[nn];
                #pragma unroll
                for (int r = 0; r < 4; r++) {
                    const int mm = m0 + wm * 64 + mi * 16 + 4 * lg + r;
                    cOut[(size_t)mm * N + nn] = acc[mi][ni][r] + bv;
                }
            }
        }
    }
}

// ---------------- kv_cum: KF[ks=2,3] = SCALE * cumsum_t(Kh[t][d] * Vh[t][d]) ----------------
__global__ void k_kvcum(const _Float16* __restrict__ Kh, const _Float16* __restrict__ Vh,
                        _Float16* __restrict__ KF)
{
    const int bh = blockIdx.x;
    const int w = threadIdx.x >> 6, d = threadIdx.x & 63;   // 16 waves
    const size_t base = (size_t)bh * T_SEQ * HD + d;
    const int CH = T_SEQ / 16;
    const int t0 = w * CH;
    float s = 0.f;
    #pragma unroll 8
    for (int i = 0; i < CH; i++) {
        size_t o = base + (size_t)(t0 + i) * HD;
        s += (float)Kh[o] * (float)Vh[o];
    }
    __shared__ float tot[16][64];
    tot[w][d] = s;
    __syncthreads();
    float acc = 0.f;
    for (int ww = 0; ww < w; ww++) acc += tot[ww][d];
    const int ksK = 2 + (d >> 5), lgK = (d & 31) >> 3, iK = d & 7;
    for (int i = 0; i < CH; i++) {
        const int t = t0 + i;
        size_t o = base + (size_t)t * HD;
        acc += (float)Kh[o] * (float)Vh[o];
        const int j = t >> 6, ct = (t >> 4) & 3;
        const int laneF = (t & 15) | (lgK << 4);
        KF[(((size_t)bh * 32 + j) * 16 + ct * 4 + ksK) * 512 + laneF * 8 + iK] =
            (_Float16)(acc * SCALE);
    }
}

// ---------------- flash attention partial (key-split, KBLK=32 double-buffered LDS) ----------------
// T3-minimum 2-phase: stage(subtile s+1) issued BEFORE compute(s); one barrier/iter —
// the compiler's vmcnt(0) drain lands after compute, so load latency hides under MFMA.
// Subtile = 32 keys: KF block (8KB) contiguous, VF = 4x1KB pieces; linear staging copy.
// LDS 16+8+4 = 28 KB -> 5 blocks/CU; VGPR ~60 (no spill).
__launch_bounds__(256, 4)
__global__ void k_attn(const _Float16* __restrict__ Qb, const _Float16* __restrict__ Tb,
                       const _Float16* __restrict__ KF, const _Float16* __restrict__ VF,
                       _Float16* __restrict__ Op0, _Float16* __restrict__ Op1,
                       _Float16* __restrict__ Op2, _Float16* __restrict__ Op3,
                       float* __restrict__ ML, int nsplit)
{
    const int bh = blockIdx.x;
    const int pair = blockIdx.y;
    const int ksel = blockIdx.z;
    const int tid = threadIdx.x;
    const int wid = tid >> 6, lane = tid & 63, lrow = lane & 15, lg = lane >> 4;
    const _Float16* qp = Qb + (size_t)bh * T_SEQ * HD;
    const _Float16* tp = Tb + (size_t)bh * T_SEQ * HD;
    const _Float16* kfb = KF + (size_t)bh * 32 * 16 * 512;
    const _Float16* vfb = VF + (size_t)bh * 32 * 8 * 512;
    _Float16* op = (ksel == 0) ? Op0 : (ksel == 1) ? Op1 : (ksel == 2) ? Op2 : Op3;
    float* ml = ML + (size_t)ksel * BHT * 2;

    __shared__ __align__(16) _Float16 ldsK[2][8 * 512];  // 16 KB dbuf: 32-key KF subtile
    __shared__ __align__(16) _Float16 ldsV[2][4 * 512];  // 8 KB dbuf: 32-key VF subtile
    __shared__ __align__(16) _Float16 lP[4][16 * 32];    // 4 KB per-wave P (swizzled)

    const h8 ones = {(_Float16)1.f, (_Float16)1.f, (_Float16)1.f, (_Float16)1.f,
                     (_Float16)1.f, (_Float16)1.f, (_Float16)1.f, (_Float16)1.f};
    const float C = SCALE * LOG2E;

    // stage subtile st into buf: K = 8KB contiguous (2 rounds), V = 4x1KB (wid-split)
    auto stage = [&](int st, int buf) {
        const _Float16* kfj = kfb + ((size_t)(st >> 1) * 16 + (st & 1) * 8) * 512;
        #pragma unroll
        for (int i = 0; i < 2; i++)
            gload16(kfj + i * 2048 + wid * 512 + lane * 8,
                    &ldsK[buf][i * 2048 + wid * 512]);
        const _Float16* vfj = vfb + ((size_t)(st >> 1) * 8 + wid * 2 + (st & 1)) * 512;
        gload16(vfj + lane * 8, &ldsV[buf][wid * 512]);
    };

    for (int half = 0; half < 2; ++half) {
        const int qi = half ? (NT - 1 - pair) : pair;
        const int q0 = qi * 64;
        const int nj = qi + 1;
        const int jbeg = (nj * ksel) / nsplit;
        const int jend = (nj * (ksel + 1)) / nsplit;
        const int sbeg = 2 * jbeg, send = 2 * jend;

        // hoisted extended-Q fragments: ks 0,1 = C*q chunks; ks 2,3 = C*q*t chunks
        const int qrow = q0 + wid * 16 + lrow;
        h8 qf[4];
        #pragma unroll
        for (int ks = 0; ks < 2; ++ks) {
            h8 qv = *(const h8*)&qp[(size_t)qrow * HD + ks * 32 + lg * 8];
            h8 tv = *(const h8*)&tp[(size_t)qrow * HD + ks * 32 + lg * 8];
            h8 a2, b2;
            #pragma unroll
            for (int i = 0; i < 8; i++) {
                float qq = (float)qv[i] * C;
                a2[i] = (_Float16)qq;
                b2[i] = (_Float16)(qq * (float)tv[i]);
            }
            qf[ks] = a2; qf[2 + ks] = b2;
        }

        float m_r[4];
        f32x4 o[4], o4;
        #pragma unroll
        for (int r = 0; r < 4; r++) m_r[r] = -__builtin_inff();
        #pragma unroll
        for (int ct = 0; ct < 4; ct++) o[ct] = (f32x4){0.f, 0.f, 0.f, 0.f};
        o4 = (f32x4){0.f, 0.f, 0.f, 0.f};

        if (sbeg < send) stage(sbeg, 0);
        __syncthreads();   // drains prologue; also protects prev half's buffers

        int cur = 0;
        for (int st = sbeg; st < send; ++st) {
            if (st + 1 < send) stage(st + 1, cur ^ 1);   // flies under compute

            f32x4 s[2];
            #pragma unroll
            for (int c2 = 0; c2 < 2; c2++) {
                const _Float16* kb = &ldsK[cur][(c2 * 4) * 512] + lane * 8;
                f32x4 sv = (f32x4){0.f, 0.f, 0.f, 0.f};
                sv = mfma_h(qf[0], *(const h8*)kb, sv);
                sv = mfma_h(qf[1], *(const h8*)(kb + 512), sv);
                sv = mfma_h(qf[2], *(const h8*)(kb + 1024), sv);
                sv = mfma_h(qf[3], *(const h8*)(kb + 1536), sv);
                s[c2] = sv;
            }
            if ((st >> 1) == qi) {   // diagonal tile: causal mask
                #pragma unroll
                for (int c2 = 0; c2 < 2; c2++)
                    #pragma unroll
                    for (int r = 0; r < 4; r++) {
                        int key = (st >> 1) * 64 + (st & 1) * 32 + c2 * 16 + lrow;
                        int qr  = q0 + wid * 16 + 4 * lg + r;
                        if (key > qr) s[c2][r] = -__builtin_inff();
                    }
            }
            // deferred max: only reduce/rescale when some score exceeds m + TAU
            float mx[4];
            #pragma unroll
            for (int r = 0; r < 4; r++) mx[r] = fmaxf(s[0][r], s[1][r]);
            bool need = (mx[0] > m_r[0] + TAU) | (mx[1] > m_r[1] + TAU) |
                        (mx[2] > m_r[2] + TAU) | (mx[3] > m_r[3] + TAU);
            if (__any(need)) {
                #pragma unroll
                for (int d = 1; d < 16; d <<= 1)
                    #pragma unroll
                    for (int r = 0; r < 4; r++) mx[r] = fmaxf(mx[r], __shfl_xor(mx[r], d, 64));
                #pragma unroll
                for (int r = 0; r < 4; r++) {
                    float mn = fmaxf(m_r[r], mx[r]);
                    float scl = __builtin_amdgcn_exp2f(m_r[r] - mn);
                    o[0][r] *= scl; o[1][r] *= scl; o[2][r] *= scl; o[3][r] *= scl;
                    o4[r] *= scl;
                    m_r[r] = mn;
                }
            }
            // P = exp2(s - m) -> swizzled wave-private LDS (16x32, 64B rows)
            #pragma unroll
            for (int c2 = 0; c2 < 2; c2++) {
                const int col = c2 * 16 + lrow;
                #pragma unroll
                for (int r = 0; r < 4; r++) {
                    float p = __builtin_amdgcn_exp2f(s[c2][r] - m_r[r]);
                    const int row = 4 * lg + r;
                    const int boff = row * 64 + ((col * 2) ^ ((row >> 2) << 4));
                    lP[wid][boff >> 1] = (_Float16)p;
                }
            }
            // P fragment (A-layout, k=0..31) from swizzled LDS
            h8 pa;
            {
                const int boff = lrow * 64 + ((lg * 16) ^ ((lrow >> 2) << 4));
                pa = *(const h8*)((const char*)lP[wid] + boff);
            }
            // O += P @ V ; row-sum l via ones-MFMA
            o4 = mfma_h(pa, ones, o4);
            #pragma unroll
            for (int ct = 0; ct < 4; ct++) {
                const _Float16* vb = &ldsV[cur][ct * 512] + lane * 8;
                o[ct] = mfma_h(pa, *(const h8*)vb, o[ct]);
            }
            __syncthreads();   // drains stage(st+1); all waves done with buf[cur]
            cur ^= 1;
        }
        // write partial: unnormalized O (f16) + per-row (m2, l)
        #pragma unroll
        for (int ct = 0; ct < 4; ct++)
            #pragma unroll
            for (int r = 0; r < 4; r++) {
                const int trow = q0 + wid * 16 + 4 * lg + r;
                const int d = ct * 16 + lrow;
                op[((size_t)bh * T_SEQ + trow) * HD + d] = (_Float16)o[ct][r];
            }
        if (lrow == 0) {
            #pragma unroll
            for (int r = 0; r < 4; r++) {
                const int trow = q0 + wid * 16 + 4 * lg + r;
                const size_t mi = ((size_t)bh * T_SEQ + trow) * 2;
                ml[mi] = m_r[r];
                ml[mi + 1] = o4[r];
            }
        }
    }
}

// ---------------- combine nsplit key-chunk partials -> AO [B,T,D] f16 ----------------
__global__ void k_combine(const _Float16* __restrict__ Op0, const _Float16* __restrict__ Op1,
                          const _Float16* __restrict__ Op2, const _Float16* __restrict__ Op3,
                          const float* __restrict__ ML, _Float16* __restrict__ AO, int nsplit)
{
    const int idx = blockIdx.x * 256 + threadIdx.x;   // over BHT*HD/8
    const int row = idx >> 3;           // bh*T + t
    const int d0 = (idx & 7) * 8;
    const int bh = row >> 11, t = row & (T_SEQ - 1);
    const int b = bh >> 4, h = bh & 15;
    const _Float16* ops[4] = {Op0, Op1, Op2, Op3};
    float m = -__builtin_inff();
    for (int c = 0; c < nsplit; c++) m = fmaxf(m, ML[(size_t)c * BHT * 2 + 2 * row]);
    float w[4], denom = 0.f;
    for (int c = 0; c < nsplit; c++) {
        w[c] = __builtin_amdgcn_exp2f(ML[(size_t)c * BHT * 2 + 2 * row] - m);
        denom += w[c] * ML[(size_t)c * BHT * 2 + 2 * row + 1];
    }
    const float inv = 1.0f / denom;
    float accv[8];
    #pragma unroll
    for (int i = 0; i < 8; i++) accv[i] = 0.f;
    for (int c = 0; c < nsplit; c++) {
        h8 a = *(const h8*)&ops[c][(size_t)row * HD + d0];
        #pragma unroll
        for (int i = 0; i < 8; i++) accv[i] += w[c] * (float)a[i];
    }
    h8 r;
    #pragma unroll
    for (int i = 0; i < 8; i++) r[i] = (_Float16)(accv[i] * inv);
    *(h8*)&AO[((size_t)(b * T_SEQ + t)) * D_MODEL + h * HD + d0] = r;
}

extern "C" void kernel_launch(void* const* d_in, const int* in_sizes, int n_in,
                              void* d_out, int out_size, void* d_ws, size_t ws_size,
                              hipStream_t stream)
{
    const float* x     = (const float*)d_in[0];
    const float* Wqkvt = (const float*)d_in[1];
    const float* bqkvt = (const float*)d_in[2];
    const float* Wout  = (const float*)d_in[3];
    const float* bout  = (const float*)d_in[4];
    float* out = (float*)d_out;

    char* ws = (char*)d_ws;
    size_t off = 0;
    auto alloc = [&](size_t bytes) {
        char* p = ws + off;
        off += (bytes + 255) & ~(size_t)255;
        return p;
    };
    const size_t SZ = (size_t)M_ROWS * D_MODEL * 2;   // 8 MiB per f16 [B,H,T,64] buffer
    _Float16* xb  = (_Float16*)alloc(SZ);              // -> Op0 after gemm1
    _Float16* wt  = (_Float16*)alloc(SZ);              // -> ML after gemm1
    _Float16* wo  = (_Float16*)alloc((size_t)D_MODEL * D_MODEL * 2);
    _Float16* Qh  = (_Float16*)alloc(SZ);
    _Float16* Kh  = (_Float16*)alloc(SZ);              // row-major k for kvcum; -> Op2 after
    _Float16* Vh  = (_Float16*)alloc(SZ);              // row-major v for kvcum; -> Op1 after
    _Float16* Th  = (_Float16*)alloc(SZ);
    _Float16* KF  = (_Float16*)alloc(SZ * 2);          // fragment-major k|kvc [bh][32][4][4][64][8]
    _Float16* VF  = (_Float16*)alloc(SZ);              // fragment-major v    [bh][32][4][2][64][8]
    _Float16* AO  = (_Float16*)alloc(SZ);
    _Float16* Op3 = (_Float16*)alloc(SZ);

    const int nsplit = 2;   // 1024 blocks, uniform; halves partial traffic

    _Float16* Op0 = xb;
    _Float16* Op1 = Vh;
    _Float16* Op2 = Kh;
    float*    ML  = (float*)wt;    // nsplit * 512 KiB of 8 MiB

    k_convert<<<4096, 256, 0, stream>>>(x, xb, M_ROWS * D_MODEL);
    k_transpose<<<dim3(128, 32), 256, 0, stream>>>(Wqkvt, wt, D_MODEL, 4 * D_MODEL);
    k_transpose<<<dim3(32, 32), 256, 0, stream>>>(Wout, wo, D_MODEL, D_MODEL);
    k_gemm<0><<<dim3(32, 32), 256, 0, stream>>>(xb, wt, M_ROWS, 4 * D_MODEL, D_MODEL,
                                                bqkvt, Qh, Kh, KF, Vh, VF, Th, nullptr);
    k_kvcum<<<BH_TOT, 1024, 0, stream>>>(Kh, Vh, KF);
    k_attn<<<dim3(BH_TOT, NT / 2, nsplit), 256, 0, stream>>>(Qh, Th, KF, VF,
                                                             Op0, Op1, Op2, Op3, ML, nsplit);
    k_combine<<<BHT * HD / 8 / 256, 256, 0, stream>>>(Op0, Op1, Op2, Op3, ML, AO, nsplit);
    k_gemm<1><<<dim3(32, 8), 256, 0, stream>>>(AO, wo, M_ROWS, D_MODEL, D_MODEL,
                                               bout, nullptr, nullptr, nullptr, nullptr,
                                               nullptr, nullptr, out);
}

// Round 18
// 171.451 us; speedup vs baseline: 1.0415x; 1.0415x over previous
//
#include <hip/hip_runtime.h>

#define T_SEQ 2048
#define D_MODEL 1024
#define NH 16
#define HD 64
#define BH_TOT 32          // B*H
#define M_ROWS 4096        // B*T
#define NT 32              // number of 64-row q tiles
#define SCALE 0.125f
#define BHT (BH_TOT * T_SEQ)
#define LOG2E 1.44269504f
#define TAU 2.885f         // defer-max threshold in log2 units (= e^2 in p-space)

typedef _Float16 h8 __attribute__((ext_vector_type(8)));
typedef _Float16 h4 __attribute__((ext_vector_type(4)));
typedef float f32x4 __attribute__((ext_vector_type(4)));

__device__ __forceinline__ f32x4 mfma_h(h8 a, h8 b, f32x4 c) {
    return __builtin_amdgcn_mfma_f32_16x16x32_f16(a, b, c, 0, 0, 0);
}

// async global->LDS, 16B per lane; LDS dest is wave-uniform base + lane*16
__device__ __forceinline__ void gload16(const _Float16* g, _Float16* l) {
    __builtin_amdgcn_global_load_lds(
        (const __attribute__((address_space(1))) unsigned int*)g,
        (__attribute__((address_space(3))) unsigned int*)l, 16, 0, 0);
}

// ---------------- convert f32 -> f16 (flat) ----------------
__global__ void k_convert(const float* __restrict__ in, _Float16* __restrict__ out, int n) {
    int i = (blockIdx.x * blockDim.x + threadIdx.x) * 4;
    if (i < n) {
        float4 v = *(const float4*)(in + i);
        h4 o;
        o[0] = (_Float16)v.x; o[1] = (_Float16)v.y;
        o[2] = (_Float16)v.z; o[3] = (_Float16)v.w;
        *(h4*)(out + i) = o;
    }
}

// ---------------- transpose+convert: in [K][N] f32 -> out [N][K] f16 ----------------
__global__ void k_transpose(const float* __restrict__ in, _Float16* __restrict__ out, int K, int N) {
    __shared__ float tile[32][33];
    int nb = blockIdx.x * 32, kb = blockIdx.y * 32;
    int tx = threadIdx.x & 31, ty = threadIdx.x >> 5;   // 256 thr: ty 0..7
    #pragma unroll
    for (int i = 0; i < 32; i += 8)
        tile[ty + i][tx] = in[(size_t)(kb + ty + i) * N + (nb + tx)];
    __syncthreads();
    #pragma unroll
    for (int i = 0; i < 32; i += 8)
        out[(size_t)(nb + ty + i) * K + (kb + tx)] = (_Float16)tile[tx][ty + i];
}

// ---------------- GEMM: C = A[M,K] @ Bt[N,K]^T + bias ----------------
// BK=64, double-buffered LDS staged via global_load_lds(16B), inverse-swizzled
// global source; fragment ds_read applies same XOR. (Best-measured structure.)
// MODE 0 epilogue: q->Qh, k->Kh + KF(fragment-major ks0,1), v->Vh + VF(fragment-major), t->Th
// MODE 1: plain f32 output C[M,N] + bias
template<int MODE>
__launch_bounds__(256, 2)
__global__ void k_gemm(const _Float16* __restrict__ A, const _Float16* __restrict__ Bt,
                       int M, int N, int K, const float* __restrict__ bias,
                       _Float16* __restrict__ qo, _Float16* __restrict__ kho,
                       _Float16* __restrict__ kfo, _Float16* __restrict__ vo,
                       _Float16* __restrict__ vfo, _Float16* __restrict__ to,
                       float* __restrict__ cOut)
{
    __shared__ __align__(16) _Float16 lA[2][128 * 64];
    __shared__ __align__(16) _Float16 lB[2][128 * 64];
    const int tid = threadIdx.x;
    const int wid = tid >> 6, lane = tid & 63, lrow = lane & 15, lg = lane >> 4;
    const int wm = wid >> 1, wn = wid & 1;
    const int m0 = blockIdx.x * 128, n0 = blockIdx.y * 128;

    f32x4 acc[4][4];
    #pragma unroll
    for (int i = 0; i < 4; i++)
        #pragma unroll
        for (int j = 0; j < 4; j++) acc[i][j] = (f32x4){0.f, 0.f, 0.f, 0.f};

    const int rin = lane >> 3, gcol = lane & 7;
    const int scol = (gcol ^ rin) * 8;          // inverse-swizzled source column
    const _Float16* gA = A + (size_t)(m0 + 32 * wid + rin) * K + scol;
    const _Float16* gB = Bt + (size_t)(n0 + 32 * wid + rin) * K + scol;

    const int r7 = lrow & 7;
    const int nk = K >> 6;

    #pragma unroll
    for (int i = 0; i < 4; i++) {
        gload16(gA + (size_t)(8 * i) * K, &lA[0][32 * wid * 64 + 8 * i * 64]);
        gload16(gB + (size_t)(8 * i) * K, &lB[0][32 * wid * 64 + 8 * i * 64]);
    }
    __syncthreads();

    for (int kt = 0; kt < nk; ++kt) {
        const int cur = kt & 1;
        if (kt + 1 < nk) {
            const size_t ko = (size_t)(kt + 1) * 64;
            #pragma unroll
            for (int i = 0; i < 4; i++) {
                gload16(gA + (size_t)(8 * i) * K + ko, &lA[cur ^ 1][32 * wid * 64 + 8 * i * 64]);
                gload16(gB + (size_t)(8 * i) * K + ko, &lB[cur ^ 1][32 * wid * 64 + 8 * i * 64]);
            }
        }
        h8 af[4][2], bfr[4][2];
        #pragma unroll
        for (int mi = 0; mi < 4; mi++) {
            const int row = wm * 64 + mi * 16 + lrow;
            af[mi][0] = *(const h8*)&lA[cur][row * 64 + ((lg ^ r7) * 8)];
            af[mi][1] = *(const h8*)&lA[cur][row * 64 + (((4 + lg) ^ r7) * 8)];
        }
        #pragma unroll
        for (int ni = 0; ni < 4; ni++) {
            const int row = wn * 64 + ni * 16 + lrow;
            bfr[ni][0] = *(const h8*)&lB[cur][row * 64 + ((lg ^ r7) * 8)];
            bfr[ni][1] = *(const h8*)&lB[cur][row * 64 + (((4 + lg) ^ r7) * 8)];
        }
        #pragma unroll
        for (int mi = 0; mi < 4; mi++)
            #pragma unroll
            for (int ni = 0; ni < 4; ni++) {
                acc[mi][ni] = mfma_h(af[mi][0], bfr[ni][0], acc[mi][ni]);
                acc[mi][ni] = mfma_h(af[mi][1], bfr[ni][1], acc[mi][ni]);
            }
        __syncthreads();
    }

    if (MODE == 0) {
        const int ssel = n0 >> 10;
        #pragma unroll
        for (int mi = 0; mi < 4; mi++) {
            #pragma unroll
            for (int ni = 0; ni < 4; ni++) {
                const int nn = n0 + wn * 64 + ni * 16 + lrow;
                const float bv = bias[nn];
                const int h = (nn >> 6) & 15, hd = nn & 63;
                const int mmb = m0 + wm * 64 + mi * 16 + 4 * lg;
                const int b = mmb >> 11, t0 = mmb & (T_SEQ - 1);
                const int bh = b * NH + h;
                const size_t rowb = (size_t)bh * T_SEQ;
                h4 hv;
                #pragma unroll
                for (int r = 0; r < 4; r++) hv[r] = (_Float16)(acc[mi][ni][r] + bv);
                if (ssel == 0) {
                    #pragma unroll
                    for (int r = 0; r < 4; r++) qo[(rowb + t0 + r) * HD + hd] = hv[r];
                } else if (ssel == 1) {
                    const int ksK = hd >> 5, lgK = (hd & 31) >> 3, iK = hd & 7;
                    #pragma unroll
                    for (int r = 0; r < 4; r++) {
                        const int t = t0 + r;
                        kho[(rowb + t) * HD + hd] = hv[r];
                        const int j = t >> 6, ct = (t >> 4) & 3;
                        const int laneF = (t & 15) | (lgK << 4);
                        kfo[(((size_t)bh * 32 + j) * 16 + ct * 4 + ksK) * 512 + laneF * 8 + iK] = hv[r];
                    }
                } else if (ssel == 2) {
                    #pragma unroll
                    for (int r = 0; r < 4; r++) vo[(rowb + t0 + r) * HD + hd] = hv[r];
                    const int ctV = hd >> 4, lrV = hd & 15;
                    const int j = t0 >> 6, ksV = (t0 >> 5) & 1, lgV = (t0 >> 3) & 3, i0 = t0 & 7;
                    const int laneF = lrV | (lgV << 4);
                    *(h4*)&vfo[(((size_t)bh * 32 + j) * 8 + ctV * 2 + ksV) * 512 + laneF * 8 + i0] = hv;
                } else {
                    #pragma unroll
                    for (int r = 0; r < 4; r++) to[(rowb + t0 + r) * HD + hd] = hv[r];
                }
            }
        }
    } else {
        #pragma unroll
        for (int mi = 0; mi < 4; mi++) {
            #pragma unroll
            for (int ni = 0; ni < 4; ni++) {
                const int nn = n0 + wn * 64 + ni * 16 + lrow;
                const float bv = bias[nn];
                #pragma unroll
                for (int r = 0; r < 4; r++) {
                    const int mm = m0 + wm * 64 + mi * 16 + 4 * lg + r;
                    cOut[(size_t)mm * N + nn] = acc[mi][ni][r] + bv;
                }
            }
        }
    }
}

// ---------------- kv_cum: KF[ks=2,3] = SCALE * cumsum_t(Kh[t][d] * Vh[t][d]) ----------------
__global__ void k_kvcum(const _Float16* __restrict__ Kh, const _Float16* __restrict__ Vh,
                        _Float16* __restrict__ KF)
{
    const int bh = blockIdx.x;
    const int w = threadIdx.x >> 6, d = threadIdx.x & 63;   // 16 waves
    const size_t base = (size_t)bh * T_SEQ * HD + d;
    const int CH = T_SEQ / 16;
    const int t0 = w * CH;
    float s = 0.f;
    #pragma unroll 8
    for (int i = 0; i < CH; i++) {
        size_t o = base + (size_t)(t0 + i) * HD;
        s += (float)Kh[o] * (float)Vh[o];
    }
    __shared__ float tot[16][64];
    tot[w][d] = s;
    __syncthreads();
    float acc = 0.f;
    for (int ww = 0; ww < w; ww++) acc += tot[ww][d];
    const int ksK = 2 + (d >> 5), lgK = (d & 31) >> 3, iK = d & 7;
    for (int i = 0; i < CH; i++) {
        const int t = t0 + i;
        size_t o = base + (size_t)t * HD;
        acc += (float)Kh[o] * (float)Vh[o];
        const int j = t >> 6, ct = (t >> 4) & 3;
        const int laneF = (t & 15) | (lgK << 4);
        KF[(((size_t)bh * 32 + j) * 16 + ct * 4 + ksK) * 512 + laneF * 8 + iK] =
            (_Float16)(acc * SCALE);
    }
}

// ---------------- flash attention partial (key-split, block-shared LDS fragment tiles) ----------------
// Fragment-major KF/VF makes the per-j staging a LINEAR copy (gload16 src = base+tid*16B,
// dest = wavebase+lane*16B — no swizzle either side); all 4 waves then read each 24KB
// tile from LDS (contiguous 1KB ds_read bursts) -> 4x less L2 read traffic than per-wave
// global fragment loads. LDS 16+8+8=32KB -> 4 blocks/CU at (256,4); VGPR ~60 (no spill).
__launch_bounds__(256, 4)
__global__ void k_attn(const _Float16* __restrict__ Qb, const _Float16* __restrict__ Tb,
                       const _Float16* __restrict__ KF, const _Float16* __restrict__ VF,
                       _Float16* __restrict__ Op0, _Float16* __restrict__ Op1,
                       _Float16* __restrict__ Op2, _Float16* __restrict__ Op3,
                       float* __restrict__ ML, int nsplit)
{
    const int bh = blockIdx.x;
    const int pair = blockIdx.y;
    const int ksel = blockIdx.z;
    const int tid = threadIdx.x;
    const int wid = tid >> 6, lane = tid & 63, lrow = lane & 15, lg = lane >> 4;
    const _Float16* qp = Qb + (size_t)bh * T_SEQ * HD;
    const _Float16* tp = Tb + (size_t)bh * T_SEQ * HD;
    const _Float16* kfb = KF + (size_t)bh * 32 * 16 * 512;
    const _Float16* vfb = VF + (size_t)bh * 32 * 8 * 512;
    _Float16* op = (ksel == 0) ? Op0 : (ksel == 1) ? Op1 : (ksel == 2) ? Op2 : Op3;
    float* ml = ML + (size_t)ksel * BHT * 2;

    __shared__ __align__(16) _Float16 ldsK[16 * 512];  // 16 KB: one j-tile of KF
    __shared__ __align__(16) _Float16 ldsV[8 * 512];   // 8 KB: one j-tile of VF
    __shared__ __align__(16) _Float16 lP[4][16 * 64];  // per-wave P buffer (swizzled)

    const h8 ones = {(_Float16)1.f, (_Float16)1.f, (_Float16)1.f, (_Float16)1.f,
                     (_Float16)1.f, (_Float16)1.f, (_Float16)1.f, (_Float16)1.f};
    const float C = SCALE * LOG2E;

    for (int half = 0; half < 2; ++half) {
        const int qi = half ? (NT - 1 - pair) : pair;
        const int q0 = qi * 64;
        const int nj = qi + 1;
        const int jbeg = (nj * ksel) / nsplit;
        const int jend = (nj * (ksel + 1)) / nsplit;

        // hoisted extended-Q fragments: ks 0,1 = C*q chunks; ks 2,3 = C*q*t chunks
        const int qrow = q0 + wid * 16 + lrow;
        h8 qf[4];
        #pragma unroll
        for (int ks = 0; ks < 2; ++ks) {
            h8 qv = *(const h8*)&qp[(size_t)qrow * HD + ks * 32 + lg * 8];
            h8 tv = *(const h8*)&tp[(size_t)qrow * HD + ks * 32 + lg * 8];
            h8 a2, b2;
            #pragma unroll
            for (int i = 0; i < 8; i++) {
                float qq = (float)qv[i] * C;
                a2[i] = (_Float16)qq;
                b2[i] = (_Float16)(qq * (float)tv[i]);
            }
            qf[ks] = a2; qf[2 + ks] = b2;
        }

        float m_r[4];
        f32x4 o[4], o4;
        #pragma unroll
        for (int r = 0; r < 4; r++) m_r[r] = -__builtin_inff();
        #pragma unroll
        for (int ct = 0; ct < 4; ct++) o[ct] = (f32x4){0.f, 0.f, 0.f, 0.f};
        o4 = (f32x4){0.f, 0.f, 0.f, 0.f};

        for (int j = jbeg; j < jend; ++j) {
            // ---- stage the j-tile (linear copy, 24 KB) ----
            __syncthreads();   // previous tile fully consumed by all waves
            {
                const _Float16* kfj = kfb + (size_t)j * 16 * 512;
                const _Float16* vfj = vfb + (size_t)j * 8 * 512;
                #pragma unroll
                for (int i = 0; i < 4; i++)
                    gload16(kfj + i * 2048 + wid * 512 + lane * 8,
                            &ldsK[i * 2048 + wid * 512]);
                #pragma unroll
                for (int i = 0; i < 2; i++)
                    gload16(vfj + i * 2048 + wid * 512 + lane * 8,
                            &ldsV[i * 2048 + wid * 512]);
            }
            __syncthreads();   // vmcnt drained by compiler before barrier

            f32x4 s[4];
            #pragma unroll
            for (int ct = 0; ct < 4; ct++) {
                const _Float16* kb = &ldsK[(ct * 4) * 512] + lane * 8;
                f32x4 sv = (f32x4){0.f, 0.f, 0.f, 0.f};
                sv = mfma_h(qf[0], *(const h8*)kb, sv);
                sv = mfma_h(qf[1], *(const h8*)(kb + 512), sv);
                sv = mfma_h(qf[2], *(const h8*)(kb + 1024), sv);
                sv = mfma_h(qf[3], *(const h8*)(kb + 1536), sv);
                s[ct] = sv;
            }
            if (j == qi) {   // diagonal tile: causal mask
                #pragma unroll
                for (int ct = 0; ct < 4; ct++)
                    #pragma unroll
                    for (int r = 0; r < 4; r++) {
                        int key = j * 64 + ct * 16 + lrow;
                        int qr  = q0 + wid * 16 + 4 * lg + r;
                        if (key > qr) s[ct][r] = -__builtin_inff();
                    }
            }
            // deferred max: only reduce/rescale when some score exceeds m + TAU
            float mx[4];
            #pragma unroll
            for (int r = 0; r < 4; r++)
                mx[r] = fmaxf(fmaxf(s[0][r], s[1][r]), fmaxf(s[2][r], s[3][r]));
            bool need = (mx[0] > m_r[0] + TAU) | (mx[1] > m_r[1] + TAU) |
                        (mx[2] > m_r[2] + TAU) | (mx[3] > m_r[3] + TAU);
            if (__any(need)) {
                #pragma unroll
                for (int d = 1; d < 16; d <<= 1)
                    #pragma unroll
                    for (int r = 0; r < 4; r++) mx[r] = fmaxf(mx[r], __shfl_xor(mx[r], d, 64));
                #pragma unroll
                for (int r = 0; r < 4; r++) {
                    float mn = fmaxf(m_r[r], mx[r]);
                    float scl = __builtin_amdgcn_exp2f(m_r[r] - mn);
                    o[0][r] *= scl; o[1][r] *= scl; o[2][r] *= scl; o[3][r] *= scl;
                    o4[r] *= scl;
                    m_r[r] = mn;
                }
            }
            // P = exp2(s - m) -> swizzled wave-private LDS
            #pragma unroll
            for (int ct = 0; ct < 4; ct++) {
                const int col = ct * 16 + lrow;
                #pragma unroll
                for (int r = 0; r < 4; r++) {
                    float p = __builtin_amdgcn_exp2f(s[ct][r] - m_r[r]);
                    const int row = 4 * lg + r;
                    const int boff = row * 128 + ((col * 2) ^ ((row & 7) << 4) ^ ((row & 12) << 3));
                    lP[wid][boff >> 1] = (_Float16)p;
                }
            }
            // P fragments (A-layout) from swizzled LDS
            h8 pa[2];
            #pragma unroll
            for (int ks = 0; ks < 2; ks++) {
                const int boff = lrow * 128 +
                    ((ks * 64 + lg * 16) ^ ((lrow & 7) << 4) ^ ((lrow & 12) << 3));
                pa[ks] = *(const h8*)((const char*)lP[wid] + boff);
            }
            // O += P @ V ; row-sum l via ones-MFMA (all cols identical)
            o4 = mfma_h(pa[0], ones, o4);
            o4 = mfma_h(pa[1], ones, o4);
            #pragma unroll
            for (int ct = 0; ct < 4; ct++) {
                const _Float16* vb = &ldsV[(ct * 2) * 512] + lane * 8;
                o[ct] = mfma_h(pa[0], *(const h8*)vb, o[ct]);
                o[ct] = mfma_h(pa[1], *(const h8*)(vb + 512), o[ct]);
            }
        }
        // write partial: unnormalized O (f16) + per-row (m2, l)
        #pragma unroll
        for (int ct = 0; ct < 4; ct++)
            #pragma unroll
            for (int r = 0; r < 4; r++) {
                const int trow = q0 + wid * 16 + 4 * lg + r;
                const int d = ct * 16 + lrow;
                op[((size_t)bh * T_SEQ + trow) * HD + d] = (_Float16)o[ct][r];
            }
        if (lrow == 0) {
            #pragma unroll
            for (int r = 0; r < 4; r++) {
                const int trow = q0 + wid * 16 + 4 * lg + r;
                const size_t mi = ((size_t)bh * T_SEQ + trow) * 2;
                ml[mi] = m_r[r];
                ml[mi + 1] = o4[r];
            }
        }
    }
}

// ---------------- combine nsplit key-chunk partials -> AO [B,T,D] f16 ----------------
__global__ void k_combine(const _Float16* __restrict__ Op0, const _Float16* __restrict__ Op1,
                          const _Float16* __restrict__ Op2, const _Float16* __restrict__ Op3,
                          const float* __restrict__ ML, _Float16* __restrict__ AO, int nsplit)
{
    const int idx = blockIdx.x * 256 + threadIdx.x;   // over BHT*HD/8
    const int row = idx >> 3;           // bh*T + t
    const int d0 = (idx & 7) * 8;
    const int bh = row >> 11, t = row & (T_SEQ - 1);
    const int b = bh >> 4, h = bh & 15;
    const _Float16* ops[4] = {Op0, Op1, Op2, Op3};
    float m = -__builtin_inff();
    for (int c = 0; c < nsplit; c++) m = fmaxf(m, ML[(size_t)c * BHT * 2 + 2 * row]);
    float w[4], denom = 0.f;
    for (int c = 0; c < nsplit; c++) {
        w[c] = __builtin_amdgcn_exp2f(ML[(size_t)c * BHT * 2 + 2 * row] - m);
        denom += w[c] * ML[(size_t)c * BHT * 2 + 2 * row + 1];
    }
    const float inv = 1.0f / denom;
    float accv[8];
    #pragma unroll
    for (int i = 0; i < 8; i++) accv[i] = 0.f;
    for (int c = 0; c < nsplit; c++) {
        h8 a = *(const h8*)&ops[c][(size_t)row * HD + d0];
        #pragma unroll
        for (int i = 0; i < 8; i++) accv[i] += w[c] * (float)a[i];
    }
    h8 r;
    #pragma unroll
    for (int i = 0; i < 8; i++) r[i] = (_Float16)(accv[i] * inv);
    *(h8*)&AO[((size_t)(b * T_SEQ + t)) * D_MODEL + h * HD + d0] = r;
}

extern "C" void kernel_launch(void* const* d_in, const int* in_sizes, int n_in,
                              void* d_out, int out_size, void* d_ws, size_t ws_size,
                              hipStream_t stream)
{
    const float* x     = (const float*)d_in[0];
    const float* Wqkvt = (const float*)d_in[1];
    const float* bqkvt = (const float*)d_in[2];
    const float* Wout  = (const float*)d_in[3];
    const float* bout  = (const float*)d_in[4];
    float* out = (float*)d_out;

    char* ws = (char*)d_ws;
    size_t off = 0;
    auto alloc = [&](size_t bytes) {
        char* p = ws + off;
        off += (bytes + 255) & ~(size_t)255;
        return p;
    };
    const size_t SZ = (size_t)M_ROWS * D_MODEL * 2;   // 8 MiB per f16 [B,H,T,64] buffer
    _Float16* xb  = (_Float16*)alloc(SZ);              // -> Op0 after gemm1
    _Float16* wt  = (_Float16*)alloc(SZ);              // -> ML after gemm1
    _Float16* wo  = (_Float16*)alloc((size_t)D_MODEL * D_MODEL * 2);
    _Float16* Qh  = (_Float16*)alloc(SZ);
    _Float16* Kh  = (_Float16*)alloc(SZ);              // row-major k for kvcum; -> Op2 after
    _Float16* Vh  = (_Float16*)alloc(SZ);              // row-major v for kvcum; -> Op1 after
    _Float16* Th  = (_Float16*)alloc(SZ);
    _Float16* KF  = (_Float16*)alloc(SZ * 2);          // fragment-major k|kvc [bh][32][4][4][64][8]
    _Float16* VF  = (_Float16*)alloc(SZ);              // fragment-major v    [bh][32][4][2][64][8]
    _Float16* AO  = (_Float16*)alloc(SZ);
    _Float16* Op3 = (_Float16*)alloc(SZ);

    const int nsplit = 2;   // 1024 blocks = exactly 4/CU, uniform; halves partial traffic

    _Float16* Op0 = xb;
    _Float16* Op1 = Vh;
    _Float16* Op2 = Kh;
    float*    ML  = (float*)wt;    // nsplit * 512 KiB of 8 MiB

    k_convert<<<4096, 256, 0, stream>>>(x, xb, M_ROWS * D_MODEL);
    k_transpose<<<dim3(128, 32), 256, 0, stream>>>(Wqkvt, wt, D_MODEL, 4 * D_MODEL);
    k_transpose<<<dim3(32, 32), 256, 0, stream>>>(Wout, wo, D_MODEL, D_MODEL);
    k_gemm<0><<<dim3(32, 32), 256, 0, stream>>>(xb, wt, M_ROWS, 4 * D_MODEL, D_MODEL,
                                                bqkvt, Qh, Kh, KF, Vh, VF, Th, nullptr);
    k_kvcum<<<BH_TOT, 1024, 0, stream>>>(Kh, Vh, KF);
    k_attn<<<dim3(BH_TOT, NT / 2, nsplit), 256, 0, stream>>>(Qh, Th, KF, VF,
                                                             Op0, Op1, Op2, Op3, ML, nsplit);
    k_combine<<<BHT * HD / 8 / 256, 256, 0, stream>>>(Op0, Op1, Op2, Op3, ML, AO, nsplit);
    k_gemm<1><<<dim3(32, 8), 256, 0, stream>>>(AO, wo, M_ROWS, D_MODEL, D_MODEL,
                                               bout, nullptr, nullptr, nullptr, nullptr,
                                               nullptr, nullptr, out);
}

// Round 19
// 171.152 us; speedup vs baseline: 1.0433x; 1.0017x over previous
//
#include <hip/hip_runtime.h>

#define T_SEQ 2048
#define D_MODEL 1024
#define NH 16
#define HD 64
#define BH_TOT 32          // B*H
#define M_ROWS 4096        // B*T
#define NT 32              // number of 64-row q tiles
#define SCALE 0.125f
#define BHT (BH_TOT * T_SEQ)
#define LOG2E 1.44269504f
#define TAU 2.885f         // defer-max threshold in log2 units (= e^2 in p-space)

typedef _Float16 h8 __attribute__((ext_vector_type(8)));
typedef _Float16 h4 __attribute__((ext_vector_type(4)));
typedef float f32x4 __attribute__((ext_vector_type(4)));

__device__ __forceinline__ f32x4 mfma_h(h8 a, h8 b, f32x4 c) {
    return __builtin_amdgcn_mfma_f32_16x16x32_f16(a, b, c, 0, 0, 0);
}

// async global->LDS, 16B per lane; LDS dest is wave-uniform base + lane*16
__device__ __forceinline__ void gload16(const _Float16* g, _Float16* l) {
    __builtin_amdgcn_global_load_lds(
        (const __attribute__((address_space(1))) unsigned int*)g,
        (__attribute__((address_space(3))) unsigned int*)l, 16, 0, 0);
}

// ---------------- convert f32 -> f16 (flat) ----------------
__global__ void k_convert(const float* __restrict__ in, _Float16* __restrict__ out, int n) {
    int i = (blockIdx.x * blockDim.x + threadIdx.x) * 4;
    if (i < n) {
        float4 v = *(const float4*)(in + i);
        h4 o;
        o[0] = (_Float16)v.x; o[1] = (_Float16)v.y;
        o[2] = (_Float16)v.z; o[3] = (_Float16)v.w;
        *(h4*)(out + i) = o;
    }
}

// ---------------- transpose+convert: in [K][N] f32 -> out [N][K] f16 ----------------
__global__ void k_transpose(const float* __restrict__ in, _Float16* __restrict__ out, int K, int N) {
    __shared__ float tile[32][33];
    int nb = blockIdx.x * 32, kb = blockIdx.y * 32;
    int tx = threadIdx.x & 31, ty = threadIdx.x >> 5;   // 256 thr: ty 0..7
    #pragma unroll
    for (int i = 0; i < 32; i += 8)
        tile[ty + i][tx] = in[(size_t)(kb + ty + i) * N + (nb + tx)];
    __syncthreads();
    #pragma unroll
    for (int i = 0; i < 32; i += 8)
        out[(size_t)(nb + ty + i) * K + (kb + tx)] = (_Float16)tile[tx][ty + i];
}

// ---------------- GEMM: C = A[M,K] @ Bt[N,K]^T + bias ----------------
// BK=64, double-buffered LDS staged via global_load_lds(16B), inverse-swizzled
// global source; fragment ds_read applies same XOR. (Best-measured structure.)
// MODE 0 epilogue: q->Qh, k->Kh + KF(fragment-major ks0,1), v->Vh + VF(fragment-major), t->Th
// MODE 1: plain f32 output C[M,N] + bias
template<int MODE>
__launch_bounds__(256, 2)
__global__ void k_gemm(const _Float16* __restrict__ A, const _Float16* __restrict__ Bt,
                       int M, int N, int K, const float* __restrict__ bias,
                       _Float16* __restrict__ qo, _Float16* __restrict__ kho,
                       _Float16* __restrict__ kfo, _Float16* __restrict__ vo,
                       _Float16* __restrict__ vfo, _Float16* __restrict__ to,
                       float* __restrict__ cOut)
{
    __shared__ __align__(16) _Float16 lA[2][128 * 64];
    __shared__ __align__(16) _Float16 lB[2][128 * 64];
    const int tid = threadIdx.x;
    const int wid = tid >> 6, lane = tid & 63, lrow = lane & 15, lg = lane >> 4;
    const int wm = wid >> 1, wn = wid & 1;
    const int m0 = blockIdx.x * 128, n0 = blockIdx.y * 128;

    f32x4 acc[4][4];
    #pragma unroll
    for (int i = 0; i < 4; i++)
        #pragma unroll
        for (int j = 0; j < 4; j++) acc[i][j] = (f32x4){0.f, 0.f, 0.f, 0.f};

    const int rin = lane >> 3, gcol = lane & 7;
    const int scol = (gcol ^ rin) * 8;          // inverse-swizzled source column
    const _Float16* gA = A + (size_t)(m0 + 32 * wid + rin) * K + scol;
    const _Float16* gB = Bt + (size_t)(n0 + 32 * wid + rin) * K + scol;

    const int r7 = lrow & 7;
    const int nk = K >> 6;

    #pragma unroll
    for (int i = 0; i < 4; i++) {
        gload16(gA + (size_t)(8 * i) * K, &lA[0][32 * wid * 64 + 8 * i * 64]);
        gload16(gB + (size_t)(8 * i) * K, &lB[0][32 * wid * 64 + 8 * i * 64]);
    }
    __syncthreads();

    for (int kt = 0; kt < nk; ++kt) {
        const int cur = kt & 1;
        if (kt + 1 < nk) {
            const size_t ko = (size_t)(kt + 1) * 64;
            #pragma unroll
            for (int i = 0; i < 4; i++) {
                gload16(gA + (size_t)(8 * i) * K + ko, &lA[cur ^ 1][32 * wid * 64 + 8 * i * 64]);
                gload16(gB + (size_t)(8 * i) * K + ko, &lB[cur ^ 1][32 * wid * 64 + 8 * i * 64]);
            }
        }
        h8 af[4][2], bfr[4][2];
        #pragma unroll
        for (int mi = 0; mi < 4; mi++) {
            const int row = wm * 64 + mi * 16 + lrow;
            af[mi][0] = *(const h8*)&lA[cur][row * 64 + ((lg ^ r7) * 8)];
            af[mi][1] = *(const h8*)&lA[cur][row * 64 + (((4 + lg) ^ r7) * 8)];
        }
        #pragma unroll
        for (int ni = 0; ni < 4; ni++) {
            const int row = wn * 64 + ni * 16 + lrow;
            bfr[ni][0] = *(const h8*)&lB[cur][row * 64 + ((lg ^ r7) * 8)];
            bfr[ni][1] = *(const h8*)&lB[cur][row * 64 + (((4 + lg) ^ r7) * 8)];
        }
        #pragma unroll
        for (int mi = 0; mi < 4; mi++)
            #pragma unroll
            for (int ni = 0; ni < 4; ni++) {
                acc[mi][ni] = mfma_h(af[mi][0], bfr[ni][0], acc[mi][ni]);
                acc[mi][ni] = mfma_h(af[mi][1], bfr[ni][1], acc[mi][ni]);
            }
        __syncthreads();
    }

    if (MODE == 0) {
        const int ssel = n0 >> 10;
        #pragma unroll
        for (int mi = 0; mi < 4; mi++) {
            #pragma unroll
            for (int ni = 0; ni < 4; ni++) {
                const int nn = n0 + wn * 64 + ni * 16 + lrow;
                const float bv = bias[nn];
                const int h = (nn >> 6) & 15, hd = nn & 63;
                const int mmb = m0 + wm * 64 + mi * 16 + 4 * lg;
                const int b = mmb >> 11, t0 = mmb & (T_SEQ - 1);
                const int bh = b * NH + h;
                const size_t rowb = (size_t)bh * T_SEQ;
                h4 hv;
                #pragma unroll
                for (int r = 0; r < 4; r++) hv[r] = (_Float16)(acc[mi][ni][r] + bv);
                if (ssel == 0) {
                    #pragma unroll
                    for (int r = 0; r < 4; r++) qo[(rowb + t0 + r) * HD + hd] = hv[r];
                } else if (ssel == 1) {
                    const int ksK = hd >> 5, lgK = (hd & 31) >> 3, iK = hd & 7;
                    #pragma unroll
                    for (int r = 0; r < 4; r++) {
                        const int t = t0 + r;
                        kho[(rowb + t) * HD + hd] = hv[r];
                        const int j = t >> 6, ct = (t >> 4) & 3;
                        const int laneF = (t & 15) | (lgK << 4);
                        kfo[(((size_t)bh * 32 + j) * 16 + ct * 4 + ksK) * 512 + laneF * 8 + iK] = hv[r];
                    }
                } else if (ssel == 2) {
                    #pragma unroll
                    for (int r = 0; r < 4; r++) vo[(rowb + t0 + r) * HD + hd] = hv[r];
                    const int ctV = hd >> 4, lrV = hd & 15;
                    const int j = t0 >> 6, ksV = (t0 >> 5) & 1, lgV = (t0 >> 3) & 3, i0 = t0 & 7;
                    const int laneF = lrV | (lgV << 4);
                    *(h4*)&vfo[(((size_t)bh * 32 + j) * 8 + ctV * 2 + ksV) * 512 + laneF * 8 + i0] = hv;
                } else {
                    #pragma unroll
                    for (int r = 0; r < 4; r++) to[(rowb + t0 + r) * HD + hd] = hv[r];
                }
            }
        }
    } else {
        #pragma unroll
        for (int mi = 0; mi < 4; mi++) {
            #pragma unroll
            for (int ni = 0; ni < 4; ni++) {
                const int nn = n0 + wn * 64 + ni * 16 + lrow;
                const float bv = bias[nn];
                #pragma unroll
                for (int r = 0; r < 4; r++) {
                    const int mm = m0 + wm * 64 + mi * 16 + 4 * lg + r;
                    cOut[(size_t)mm * N + nn] = acc[mi][ni][r] + bv;
                }
            }
        }
    }
}

// ---------------- kv_cum: KF[ks=2,3] = SCALE * cumsum_t(Kh[t][d] * Vh[t][d]) ----------------
__global__ void k_kvcum(const _Float16* __restrict__ Kh, const _Float16* __restrict__ Vh,
                        _Float16* __restrict__ KF)
{
    const int bh = blockIdx.x;
    const int w = threadIdx.x >> 6, d = threadIdx.x & 63;   // 16 waves
    const size_t base = (size_t)bh * T_SEQ * HD + d;
    const int CH = T_SEQ / 16;
    const int t0 = w * CH;
    float s = 0.f;
    #pragma unroll 8
    for (int i = 0; i < CH; i++) {
        size_t o = base + (size_t)(t0 + i) * HD;
        s += (float)Kh[o] * (float)Vh[o];
    }
    __shared__ float tot[16][64];
    tot[w][d] = s;
    __syncthreads();
    float acc = 0.f;
    for (int ww = 0; ww < w; ww++) acc += tot[ww][d];
    const int ksK = 2 + (d >> 5), lgK = (d & 31) >> 3, iK = d & 7;
    for (int i = 0; i < CH; i++) {
        const int t = t0 + i;
        size_t o = base + (size_t)t * HD;
        acc += (float)Kh[o] * (float)Vh[o];
        const int j = t >> 6, ct = (t >> 4) & 3;
        const int laneF = (t & 15) | (lgK << 4);
        KF[(((size_t)bh * 32 + j) * 16 + ct * 4 + ksK) * 512 + laneF * 8 + iK] =
            (_Float16)(acc * SCALE);
    }
}

// ---------------- flash attention partial (key-split, block-shared LDS fragment tiles) ----------------
// Fragment-major KF/VF makes the per-j staging a LINEAR copy (gload16 src = base+tid*16B,
// dest = wavebase+lane*16B — no swizzle either side); all 4 waves then read each 24KB
// tile from LDS (contiguous 1KB ds_read bursts) -> 4x less L2 read traffic than per-wave
// global fragment loads. LDS 16+8+8=32KB -> 4 blocks/CU at (256,4); VGPR 60 (no spill).
__launch_bounds__(256, 4)
__global__ void k_attn(const _Float16* __restrict__ Qb, const _Float16* __restrict__ Tb,
                       const _Float16* __restrict__ KF, const _Float16* __restrict__ VF,
                       _Float16* __restrict__ Op0, _Float16* __restrict__ Op1,
                       _Float16* __restrict__ Op2, _Float16* __restrict__ Op3,
                       float* __restrict__ ML, int nsplit)
{
    const int bh = blockIdx.x;
    const int pair = blockIdx.y;
    const int ksel = blockIdx.z;
    const int tid = threadIdx.x;
    const int wid = tid >> 6, lane = tid & 63, lrow = lane & 15, lg = lane >> 4;
    const _Float16* qp = Qb + (size_t)bh * T_SEQ * HD;
    const _Float16* tp = Tb + (size_t)bh * T_SEQ * HD;
    const _Float16* kfb = KF + (size_t)bh * 32 * 16 * 512;
    const _Float16* vfb = VF + (size_t)bh * 32 * 8 * 512;
    _Float16* op = (ksel == 0) ? Op0 : (ksel == 1) ? Op1 : (ksel == 2) ? Op2 : Op3;
    float* ml = ML + (size_t)ksel * BHT * 2;

    __shared__ __align__(16) _Float16 ldsK[16 * 512];  // 16 KB: one j-tile of KF
    __shared__ __align__(16) _Float16 ldsV[8 * 512];   // 8 KB: one j-tile of VF
    __shared__ __align__(16) _Float16 lP[4][16 * 64];  // per-wave P buffer (swizzled)

    const h8 ones = {(_Float16)1.f, (_Float16)1.f, (_Float16)1.f, (_Float16)1.f,
                     (_Float16)1.f, (_Float16)1.f, (_Float16)1.f, (_Float16)1.f};
    const float C = SCALE * LOG2E;

    for (int half = 0; half < 2; ++half) {
        const int qi = half ? (NT - 1 - pair) : pair;
        const int q0 = qi * 64;
        const int nj = qi + 1;
        const int jbeg = (nj * ksel) / nsplit;
        const int jend = (nj * (ksel + 1)) / nsplit;

        // hoisted extended-Q fragments: ks 0,1 = C*q chunks; ks 2,3 = C*q*t chunks
        const int qrow = q0 + wid * 16 + lrow;
        h8 qf[4];
        #pragma unroll
        for (int ks = 0; ks < 2; ++ks) {
            h8 qv = *(const h8*)&qp[(size_t)qrow * HD + ks * 32 + lg * 8];
            h8 tv = *(const h8*)&tp[(size_t)qrow * HD + ks * 32 + lg * 8];
            h8 a2, b2;
            #pragma unroll
            for (int i = 0; i < 8; i++) {
                float qq = (float)qv[i] * C;
                a2[i] = (_Float16)qq;
                b2[i] = (_Float16)(qq * (float)tv[i]);
            }
            qf[ks] = a2; qf[2 + ks] = b2;
        }

        float m_r[4];
        f32x4 o[4], o4;
        #pragma unroll
        for (int r = 0; r < 4; r++) m_r[r] = -__builtin_inff();
        #pragma unroll
        for (int ct = 0; ct < 4; ct++) o[ct] = (f32x4){0.f, 0.f, 0.f, 0.f};
        o4 = (f32x4){0.f, 0.f, 0.f, 0.f};

        for (int j = jbeg; j < jend; ++j) {
            // ---- stage the j-tile (linear copy, 24 KB) ----
            __syncthreads();   // previous tile fully consumed by all waves
            {
                const _Float16* kfj = kfb + (size_t)j * 16 * 512;
                const _Float16* vfj = vfb + (size_t)j * 8 * 512;
                #pragma unroll
                for (int i = 0; i < 4; i++)
                    gload16(kfj + i * 2048 + wid * 512 + lane * 8,
                            &ldsK[i * 2048 + wid * 512]);
                #pragma unroll
                for (int i = 0; i < 2; i++)
                    gload16(vfj + i * 2048 + wid * 512 + lane * 8,
                            &ldsV[i * 2048 + wid * 512]);
            }
            __syncthreads();   // vmcnt drained by compiler before barrier

            f32x4 s[4];
            #pragma unroll
            for (int ct = 0; ct < 4; ct++) {
                const _Float16* kb = &ldsK[(ct * 4) * 512] + lane * 8;
                f32x4 sv = (f32x4){0.f, 0.f, 0.f, 0.f};
                sv = mfma_h(qf[0], *(const h8*)kb, sv);
                sv = mfma_h(qf[1], *(const h8*)(kb + 512), sv);
                sv = mfma_h(qf[2], *(const h8*)(kb + 1024), sv);
                sv = mfma_h(qf[3], *(const h8*)(kb + 1536), sv);
                s[ct] = sv;
            }
            if (j == qi) {   // diagonal tile: causal mask
                #pragma unroll
                for (int ct = 0; ct < 4; ct++)
                    #pragma unroll
                    for (int r = 0; r < 4; r++) {
                        int key = j * 64 + ct * 16 + lrow;
                        int qr  = q0 + wid * 16 + 4 * lg + r;
                        if (key > qr) s[ct][r] = -__builtin_inff();
                    }
            }
            // deferred max: only reduce/rescale when some score exceeds m + TAU
            float mx[4];
            #pragma unroll
            for (int r = 0; r < 4; r++)
                mx[r] = fmaxf(fmaxf(s[0][r], s[1][r]), fmaxf(s[2][r], s[3][r]));
            bool need = (mx[0] > m_r[0] + TAU) | (mx[1] > m_r[1] + TAU) |
                        (mx[2] > m_r[2] + TAU) | (mx[3] > m_r[3] + TAU);
            if (__any(need)) {
                #pragma unroll
                for (int d = 1; d < 16; d <<= 1)
                    #pragma unroll
                    for (int r = 0; r < 4; r++) mx[r] = fmaxf(mx[r], __shfl_xor(mx[r], d, 64));
                #pragma unroll
                for (int r = 0; r < 4; r++) {
                    float mn = fmaxf(m_r[r], mx[r]);
                    float scl = __builtin_amdgcn_exp2f(m_r[r] - mn);
                    o[0][r] *= scl; o[1][r] *= scl; o[2][r] *= scl; o[3][r] *= scl;
                    o4[r] *= scl;
                    m_r[r] = mn;
                }
            }
            // P = exp2(s - m) -> swizzled wave-private LDS
            #pragma unroll
            for (int ct = 0; ct < 4; ct++) {
                const int col = ct * 16 + lrow;
                #pragma unroll
                for (int r = 0; r < 4; r++) {
                    float p = __builtin_amdgcn_exp2f(s[ct][r] - m_r[r]);
                    const int row = 4 * lg + r;
                    const int boff = row * 128 + ((col * 2) ^ ((row & 7) << 4) ^ ((row & 12) << 3));
                    lP[wid][boff >> 1] = (_Float16)p;
                }
            }
            // P fragments (A-layout) from swizzled LDS
            h8 pa[2];
            #pragma unroll
            for (int ks = 0; ks < 2; ks++) {
                const int boff = lrow * 128 +
                    ((ks * 64 + lg * 16) ^ ((lrow & 7) << 4) ^ ((lrow & 12) << 3));
                pa[ks] = *(const h8*)((const char*)lP[wid] + boff);
            }
            // O += P @ V ; row-sum l via ones-MFMA (all cols identical)
            o4 = mfma_h(pa[0], ones, o4);
            o4 = mfma_h(pa[1], ones, o4);
            #pragma unroll
            for (int ct = 0; ct < 4; ct++) {
                const _Float16* vb = &ldsV[(ct * 2) * 512] + lane * 8;
                o[ct] = mfma_h(pa[0], *(const h8*)vb, o[ct]);
                o[ct] = mfma_h(pa[1], *(const h8*)(vb + 512), o[ct]);
            }
        }
        // write partial: unnormalized O (f16) + per-row (m2, l)
        #pragma unroll
        for (int ct = 0; ct < 4; ct++)
            #pragma unroll
            for (int r = 0; r < 4; r++) {
                const int trow = q0 + wid * 16 + 4 * lg + r;
                const int d = ct * 16 + lrow;
                op[((size_t)bh * T_SEQ + trow) * HD + d] = (_Float16)o[ct][r];
            }
        if (lrow == 0) {
            #pragma unroll
            for (int r = 0; r < 4; r++) {
                const int trow = q0 + wid * 16 + 4 * lg + r;
                const size_t mi = ((size_t)bh * T_SEQ + trow) * 2;
                ml[mi] = m_r[r];
                ml[mi + 1] = o4[r];
            }
        }
    }
}

// ---------------- combine nsplit key-chunk partials -> AO [B,T,D] f16 ----------------
__global__ void k_combine(const _Float16* __restrict__ Op0, const _Float16* __restrict__ Op1,
                          const _Float16* __restrict__ Op2, const _Float16* __restrict__ Op3,
                          const float* __restrict__ ML, _Float16* __restrict__ AO, int nsplit)
{
    const int idx = blockIdx.x * 256 + threadIdx.x;   // over BHT*HD/8
    const int row = idx >> 3;           // bh*T + t
    const int d0 = (idx & 7) * 8;
    const int bh = row >> 11, t = row & (T_SEQ - 1);
    const int b = bh >> 4, h = bh & 15;
    const _Float16* ops[4] = {Op0, Op1, Op2, Op3};
    float m = -__builtin_inff();
    for (int c = 0; c < nsplit; c++) m = fmaxf(m, ML[(size_t)c * BHT * 2 + 2 * row]);
    float w[4], denom = 0.f;
    for (int c = 0; c < nsplit; c++) {
        w[c] = __builtin_amdgcn_exp2f(ML[(size_t)c * BHT * 2 + 2 * row] - m);
        denom += w[c] * ML[(size_t)c * BHT * 2 + 2 * row + 1];
    }
    const float inv = 1.0f / denom;
    float accv[8];
    #pragma unroll
    for (int i = 0; i < 8; i++) accv[i] = 0.f;
    for (int c = 0; c < nsplit; c++) {
        h8 a = *(const h8*)&ops[c][(size_t)row * HD + d0];
        #pragma unroll
        for (int i = 0; i < 8; i++) accv[i] += w[c] * (float)a[i];
    }
    h8 r;
    #pragma unroll
    for (int i = 0; i < 8; i++) r[i] = (_Float16)(accv[i] * inv);
    *(h8*)&AO[((size_t)(b * T_SEQ + t)) * D_MODEL + h * HD + d0] = r;
}

extern "C" void kernel_launch(void* const* d_in, const int* in_sizes, int n_in,
                              void* d_out, int out_size, void* d_ws, size_t ws_size,
                              hipStream_t stream)
{
    const float* x     = (const float*)d_in[0];
    const float* Wqkvt = (const float*)d_in[1];
    const float* bqkvt = (const float*)d_in[2];
    const float* Wout  = (const float*)d_in[3];
    const float* bout  = (const float*)d_in[4];
    float* out = (float*)d_out;

    char* ws = (char*)d_ws;
    size_t off = 0;
    auto alloc = [&](size_t bytes) {
        char* p = ws + off;
        off += (bytes + 255) & ~(size_t)255;
        return p;
    };
    const size_t SZ = (size_t)M_ROWS * D_MODEL * 2;   // 8 MiB per f16 [B,H,T,64] buffer
    _Float16* xb  = (_Float16*)alloc(SZ);              // -> Op0 after gemm1
    _Float16* wt  = (_Float16*)alloc(SZ);              // -> ML after gemm1
    _Float16* wo  = (_Float16*)alloc((size_t)D_MODEL * D_MODEL * 2);
    _Float16* Qh  = (_Float16*)alloc(SZ);
    _Float16* Kh  = (_Float16*)alloc(SZ);              // row-major k for kvcum; -> Op2 after
    _Float16* Vh  = (_Float16*)alloc(SZ);              // row-major v for kvcum; -> Op1 after
    _Float16* Th  = (_Float16*)alloc(SZ);
    _Float16* KF  = (_Float16*)alloc(SZ * 2);          // fragment-major k|kvc [bh][32][4][4][64][8]
    _Float16* VF  = (_Float16*)alloc(SZ);              // fragment-major v    [bh][32][4][2][64][8]
    _Float16* AO  = (_Float16*)alloc(SZ);
    _Float16* Op3 = (_Float16*)alloc(SZ);

    const int nsplit = 2;   // 1024 blocks = exactly 4/CU, uniform; halves partial traffic

    _Float16* Op0 = xb;
    _Float16* Op1 = Vh;
    _Float16* Op2 = Kh;
    float*    ML  = (float*)wt;    // nsplit * 512 KiB of 8 MiB

    k_convert<<<4096, 256, 0, stream>>>(x, xb, M_ROWS * D_MODEL);
    k_transpose<<<dim3(128, 32), 256, 0, stream>>>(Wqkvt, wt, D_MODEL, 4 * D_MODEL);
    k_transpose<<<dim3(32, 32), 256, 0, stream>>>(Wout, wo, D_MODEL, D_MODEL);
    k_gemm<0><<<dim3(32, 32), 256, 0, stream>>>(xb, wt, M_ROWS, 4 * D_MODEL, D_MODEL,
                                                bqkvt, Qh, Kh, KF, Vh, VF, Th, nullptr);
    k_kvcum<<<BH_TOT, 1024, 0, stream>>>(Kh, Vh, KF);
    k_attn<<<dim3(BH_TOT, NT / 2, nsplit), 256, 0, stream>>>(Qh, Th, KF, VF,
                                                             Op0, Op1, Op2, Op3, ML, nsplit);
    k_combine<<<BHT * HD / 8 / 256, 256, 0, stream>>>(Op0, Op1, Op2, Op3, ML, AO, nsplit);
    k_gemm<1><<<dim3(32, 8), 256, 0, stream>>>(AO, wo, M_ROWS, D_MODEL, D_MODEL,
                                               bout, nullptr, nullptr, nullptr, nullptr,
                                               nullptr, nullptr, out);
}